// Round 1
// baseline (271.774 us; speedup 1.0000x reference)
//
#include <hip/hip_runtime.h>

// Greedy dedup = masked argmax scan. B=65536 rows, S=25 steps, V=25 vocab.
// One thread per row: stream the row step-by-step (25 floats live in regs),
// 32-bit used-mask, register argmax. Double-buffer next step's 25 loads so
// the wave keeps >=25 independent 4B gathers in flight (memory-bound kernel,
// 1 wave/SIMD -> latency hiding must come from ILP/MLP).

#define SLEN 25
#define VOCAB 25

__global__ __launch_bounds__(256) void greedy_dedup_kernel(
    const float* __restrict__ m, float* __restrict__ out, int B) {
  int b = blockIdx.x * blockDim.x + threadIdx.x;
  if (b >= B) return;

  const float* row = m + (long long)b * (SLEN * VOCAB);
  float* act_out = out + (long long)b * SLEN;                       // actions chunk
  float* val_out = out + (long long)B * SLEN + (long long)b * SLEN; // scores chunk

  float cur[VOCAB];
  float nxt[VOCAB];

#pragma unroll
  for (int v = 0; v < VOCAB; ++v) cur[v] = row[v];

  unsigned used = 0u;

  // Outer loop NOT unrolled (keeps I-cache footprint small); inner loops
  // fully unrolled so cur[]/nxt[] stay in VGPRs (constant indices only).
  for (int s = 0; s < SLEN; ++s) {
    // Prefetch next step's scores before the sequential argmax chain.
    if (s + 1 < SLEN) {
      const float* p = row + (s + 1) * VOCAB;
#pragma unroll
      for (int v = 0; v < VOCAB; ++v) nxt[v] = p[v];
    }

    // Masked argmax over 25 candidates; ascending scan + strict '>' matches
    // jnp.argmax first-max tie-breaking.
    float best = -3.402823466e38f;
    int bi = 0;
#pragma unroll
    for (int v = 0; v < VOCAB; ++v) {
      bool free_v = ((used >> v) & 1u) == 0u;
      if (free_v && cur[v] > best) { best = cur[v]; bi = v; }
    }

    used |= (1u << bi);
    act_out[s] = (float)bi;   // int32 action, exactly representable in fp32
    val_out[s] = best;        // original (unmasked) score at selected index

#pragma unroll
    for (int v = 0; v < VOCAB; ++v) cur[v] = nxt[v];
  }
}

extern "C" void kernel_launch(void* const* d_in, const int* in_sizes, int n_in,
                              void* d_out, int out_size, void* d_ws, size_t ws_size,
                              hipStream_t stream) {
  const float* m = (const float*)d_in[0];
  float* out = (float*)d_out;
  int B = in_sizes[0] / (SLEN * VOCAB);  // 65536

  int block = 256;
  int grid = (B + block - 1) / block;    // 256 blocks -> 1 per CU
  greedy_dedup_kernel<<<grid, block, 0, stream>>>(m, out, B);
}

// Round 2
// 244.493 us; speedup vs baseline: 1.1116x; 1.1116x over previous
//
#include <hip/hip_runtime.h>
#include <stdint.h>

// Greedy dedup = masked argmax scan. B=65536 rows, S=25 steps, V=25 vocab.
// R1 lesson (rocprof): direct per-thread gathers = 64 lines/load-instr ->
// request-throughput bound (~67us of line requests/CU), and scattered 4B
// stores caused 11x write amplification (WRITE_SIZE 143MB vs 13MB ideal).
//
// R2 structure: block = 256 rows. Per step, global_load_lds DMAs the block's
// step-slice (256 rows x 25 floats = 25.6KB) into double-buffered LDS with
// lane-consecutive addresses (HW-coalesced full lines, async, no VGPR
// round-trip). Per-thread register argmax reads its 25 floats from LDS
// (stride 25 = odd -> 2 lanes/bank = free). Outputs staged in LDS, then
// copied out fully coalesced (each HBM line written exactly once).

#define S_LEN 25
#define VOCAB 25
#define ROWS_PER_BLOCK 256
#define THREADS 256
#define WAVES 4                                   // THREADS/64
#define DW_PER_STEP (ROWS_PER_BLOCK * VOCAB)      // 6400 dwords / block-step
#define DW_PER_WAVE (DW_PER_STEP / WAVES)         // 1600
#define J_ITERS (DW_PER_WAVE / 64)                // 25 load instrs / wave-step

__device__ __forceinline__ void gld_dword(const float* g, float* l) {
  // async global->LDS DMA, 4B/lane; LDS dest = wave-uniform base + lane*4
  __builtin_amdgcn_global_load_lds(
      (const __attribute__((address_space(1))) void*)g,
      (__attribute__((address_space(3))) void*)l, 4, 0, 0);
}

__global__ __launch_bounds__(THREADS) void greedy_dedup_kernel(
    const float* __restrict__ m, float* __restrict__ out, int B) {
  __shared__ float buf[2][DW_PER_STEP];   // double-buffered input step-slices
  __shared__ float actbuf[DW_PER_STEP];   // staged outputs (row-major [256][25])
  __shared__ float valbuf[DW_PER_STEP];

  const int t = threadIdx.x;
  const int lane = t & 63;
  const int wv = t >> 6;
  const long long blk0 = (long long)blockIdx.x * ROWS_PER_BLOCK;
  const float* bb = m + blk0 * (S_LEN * VOCAB);

  // Per-lane global source pointers for the 25 DMA issues per step.
  // LDS layout per step-slice is [row_local][v] packed = linear dword order,
  // so lane addresses must follow that same linear order. row = linear/25.
  const float* ga[J_ITERS];
#pragma unroll
  for (int j = 0; j < J_ITERS; ++j) {
    int linear = wv * DW_PER_WAVE + j * 64 + lane;  // dword idx in step-slice
    int row = linear / VOCAB;
    int v = linear - row * VOCAB;
    ga[j] = bb + row * (S_LEN * VOCAB) + v;         // step-0 address
  }

  // Preload step 0 into buf[0].
#pragma unroll
  for (int j = 0; j < J_ITERS; ++j) {
    gld_dword(ga[j], &buf[0][wv * DW_PER_WAVE + j * 64]);
    ga[j] += VOCAB;                                 // advance to step 1
  }
  __syncthreads();

  unsigned used = 0u;
  for (int s = 0; s < S_LEN; ++s) {
    // Kick off next step's DMA before the argmax so it overlaps compute.
    if (s + 1 < S_LEN) {
      float* dst = buf[(s + 1) & 1];
#pragma unroll
      for (int j = 0; j < J_ITERS; ++j) {
        gld_dword(ga[j], &dst[wv * DW_PER_WAVE + j * 64]);
        ga[j] += VOCAB;
      }
    }

    // Masked argmax over this thread's 25 candidates (LDS, conflict-free).
    // Ascending scan + strict '>' == jnp.argmax first-max tie-breaking.
    const float* src = buf[s & 1] + t * VOCAB;
    float best = -3.402823466e38f;
    int bi = 0;
#pragma unroll
    for (int v = 0; v < VOCAB; ++v) {
      float x = src[v];
      bool free_v = ((used >> v) & 1u) == 0u;
      if (free_v && x > best) { best = x; bi = v; }
    }
    used |= (1u << bi);
    actbuf[t * VOCAB + s] = (float)bi;   // exact small int in fp32
    valbuf[t * VOCAB + s] = best;        // original score at selected index
    __syncthreads();  // next-step DMA done + this buffer's reads drained
  }

  // Coalesced copy-out: block's chunks are contiguous 6400-dword regions,
  // LDS layout matches global linear order exactly.
  float* gact = out + blk0 * S_LEN;
  float* gval = out + (long long)B * S_LEN + blk0 * S_LEN;
#pragma unroll
  for (int k = 0; k < S_LEN; ++k) {
    int idx = t + k * THREADS;
    gact[idx] = actbuf[idx];
    gval[idx] = valbuf[idx];
  }
}

extern "C" void kernel_launch(void* const* d_in, const int* in_sizes, int n_in,
                              void* d_out, int out_size, void* d_ws, size_t ws_size,
                              hipStream_t stream) {
  const float* m = (const float*)d_in[0];
  float* out = (float*)d_out;
  int B = in_sizes[0] / (S_LEN * VOCAB);           // 65536
  int grid = B / ROWS_PER_BLOCK;                   // 256 blocks, exact
  greedy_dedup_kernel<<<grid, THREADS, 0, stream>>>(m, out, B);
}

// Round 3
// 232.649 us; speedup vs baseline: 1.1682x; 1.0509x over previous
//
#include <hip/hip_runtime.h>
#include <stdint.h>

// Greedy dedup = masked argmax scan. B=65536 rows, S=25 steps, V=25 vocab.
//
// R1 lesson: per-thread 4B gathers -> 64 distinct lines per wave-instr,
//   ~160K line-requests/CU, request-throughput bound (~1 req/cyc/CU).
// R2 lesson: global_load_lds width=4 with lane-consecutive addresses did NOT
//   fix it (kernel ~85-90us) -> working theory: the width-4 LDS-DMA path
//   issues per-lane requests, no line coalescing.
// R3: stage via regular global_load_dword -> VGPR -> ds_write (known-good
//   coalescer: 64 consecutive dwords/instr, each line requested once), and
//   use 1-wave blocks so there is no inter-wave barrier coupling.
//
// Block = 1 wave = 64 threads = 64 rows. Per step, the wave loads the 64-row
// step-slice (1600 dwords, lane-linear over the strided [row][25] region) into
// VGPRs (25 loads/thread, issued BEFORE the argmax so latency overlaps
// compute), writes it to the next LDS buffer, argmaxes from the current one.
// Outputs staged in LDS ([row][s] layout), copied out fully coalesced.

#define S_LEN 25
#define VOCAB 25
#define ROWS 64          // rows per block == threads per block (1 wave)
#define SLICE (ROWS * VOCAB)   // 1600 dwords per step-slice
#define J_ITERS (SLICE / 64)   // 25 load slots per thread per step

__global__ __launch_bounds__(64) void greedy_dedup_kernel(
    const float* __restrict__ m, float* __restrict__ out, int B) {
  __shared__ float buf[2][SLICE];   // 2 x 6.4 KB input step-slices
  __shared__ float abuf[SLICE];     // 6.4 KB staged actions [row][s]
  __shared__ float vbuf[SLICE];     // 6.4 KB staged scores  [row][s]

  const int t = threadIdx.x;                       // 0..63, == lane
  const long long blk0 = (long long)blockIdx.x * ROWS;
  const float* base = m + blk0 * (S_LEN * VOCAB);  // block's contiguous region

  // Step-0 dword offsets for this thread's 25 staging slots. Slot q = j*64+t
  // covers the step-slice linearly; row = q/25, v = q%25. Lane-consecutive q
  // -> (mostly) consecutive global addresses -> full line coalescing.
  int off0[J_ITERS];
#pragma unroll
  for (int j = 0; j < J_ITERS; ++j) {
    int q = j * 64 + t;
    int row = q / VOCAB;
    int v = q - row * VOCAB;
    off0[j] = row * (S_LEN * VOCAB) + v;   // + s*25 per step
  }

  float pf[J_ITERS];

  // Preload step 0.
#pragma unroll
  for (int j = 0; j < J_ITERS; ++j) pf[j] = base[off0[j]];
#pragma unroll
  for (int j = 0; j < J_ITERS; ++j) buf[0][j * 64 + t] = pf[j];
  __syncthreads();

  unsigned used = 0u;
  for (int s = 0; s < S_LEN; ++s) {
    // Issue next step's 25 loads before the argmax (latency overlaps compute).
    if (s + 1 < S_LEN) {
      const int soff = (s + 1) * VOCAB;
#pragma unroll
      for (int j = 0; j < J_ITERS; ++j) pf[j] = base[off0[j] + soff];
    }

    // Masked argmax over this row's 25 candidates (LDS stride 25 = odd ->
    // 2 lanes/bank = free). Ascending scan + strict '>' == jnp.argmax
    // first-max tie-breaking. best = original (unmasked) score.
    const float* src = buf[s & 1] + t * VOCAB;
    float best = -3.402823466e38f;
    int bi = 0;
#pragma unroll
    for (int v = 0; v < VOCAB; ++v) {
      float x = src[v];
      bool free_v = ((used >> v) & 1u) == 0u;
      if (free_v && x > best) { best = x; bi = v; }
    }
    used |= (1u << bi);
    abuf[t * VOCAB + s] = (float)bi;   // exact small int in fp32
    vbuf[t * VOCAB + s] = best;

    // Commit prefetched slice to the other buffer (vmcnt wait lands here).
    if (s + 1 < S_LEN) {
      float* dst = buf[(s + 1) & 1];
#pragma unroll
      for (int j = 0; j < J_ITERS; ++j) dst[j * 64 + t] = pf[j];
    }
    __syncthreads();   // 1-wave block: near-free; orders cross-lane LDS use
  }

  // Coalesced copy-out: block's act/val chunks are contiguous 1600-dword
  // regions and the LDS [row][s] layout matches global linear order.
  float* gact = out + blk0 * S_LEN;
  float* gval = out + (long long)B * S_LEN + blk0 * S_LEN;
#pragma unroll
  for (int k = 0; k < J_ITERS; ++k) {
    int idx = k * 64 + t;
    gact[idx] = abuf[idx];
    gval[idx] = vbuf[idx];
  }
}

extern "C" void kernel_launch(void* const* d_in, const int* in_sizes, int n_in,
                              void* d_out, int out_size, void* d_ws, size_t ws_size,
                              hipStream_t stream) {
  const float* m = (const float*)d_in[0];
  float* out = (float*)d_out;
  int B = in_sizes[0] / (S_LEN * VOCAB);   // 65536
  int grid = B / ROWS;                     // 1024 one-wave blocks, 4/CU
  greedy_dedup_kernel<<<grid, ROWS, 0, stream>>>(m, out, B);
}